// Round 1
// baseline (2102.785 us; speedup 1.0000x reference)
//
#include <hip/hip_runtime.h>
#include <math.h>

typedef unsigned short u16;
typedef __attribute__((ext_vector_type(8))) __bf16 bf16x8v;
typedef __attribute__((ext_vector_type(8))) unsigned short ushort8v;
typedef __attribute__((ext_vector_type(4))) float f32x4v;

#define D_EMBD 1024
#define NHEADS 16
#define DHEAD  64
#define DFF    4096
#define BATCHN 2
#define SEQL   2048
#define TOK    (BATCHN*SEQL)

#define EPI_F32_BIAS_RES 1
#define EPI_BF16_GELU    2
#define EPI_BF16_PLAIN   3

__device__ __forceinline__ float bf2f(u16 s) {
  return __builtin_bit_cast(float, (unsigned)s << 16);
}
__device__ __forceinline__ u16 f2bf(float f) {
  unsigned u = __builtin_bit_cast(unsigned, f);
  unsigned r = u + 0x7fffu + ((u >> 16) & 1u);
  return (u16)(r >> 16);
}

// f32 -> bf16 elementwise (weights)
__global__ __launch_bounds__(256) void cvt_kernel(const float* __restrict__ src,
                                                  u16* __restrict__ dst, int n) {
  int i = blockIdx.x * 256 + threadIdx.x;
  if (i < n) dst[i] = f2bf(src[i]);
}

// LayerNorm over D=1024, one block per row, writes bf16
__global__ __launch_bounds__(256) void ln_kernel(const float* __restrict__ x,
                                                 const float* __restrict__ sc,
                                                 const float* __restrict__ sh,
                                                 u16* __restrict__ out) {
  int row = blockIdx.x, tid = threadIdx.x;
  const float4* xr = (const float4*)(x + (size_t)row * D_EMBD);
  float4 v = xr[tid];
  float s  = (v.x + v.y) + (v.z + v.w);
  float s2 = (v.x * v.x + v.y * v.y) + (v.z * v.z + v.w * v.w);
#pragma unroll
  for (int off = 32; off; off >>= 1) {
    s  += __shfl_xor(s, off, 64);
    s2 += __shfl_xor(s2, off, 64);
  }
  __shared__ float rs[4], rs2[4];
  int wave = tid >> 6, lane = tid & 63;
  if (lane == 0) { rs[wave] = s; rs2[wave] = s2; }
  __syncthreads();
  s  = (rs[0] + rs[1]) + (rs[2] + rs[3]);
  s2 = (rs2[0] + rs2[1]) + (rs2[2] + rs2[3]);
  float mean = s * (1.f / 1024.f);
  float var  = s2 * (1.f / 1024.f) - mean * mean;
  float rstd = rsqrtf(var + 1e-6f);
  float4 scv = ((const float4*)sc)[tid];
  float4 shv = ((const float4*)sh)[tid];
  u16* op = out + (size_t)row * D_EMBD + tid * 4;
  op[0] = f2bf((v.x - mean) * rstd * scv.x + shv.x);
  op[1] = f2bf((v.y - mean) * rstd * scv.y + shv.y);
  op[2] = f2bf((v.z - mean) * rstd * scv.z + shv.z);
  op[3] = f2bf((v.w - mean) * rstd * scv.w + shv.w);
}

// C[M,N] = A[M,K] @ W[N,K]^T, bf16 inputs, f32 accumulate, fused epilogues.
// 128x128 block tile, 4 waves (2x2), 4x4 of 16x16x32 MFMA per wave, BK=64.
// LDS is stored in fragment order: chunk idx = ((g*2+kk)*64 + quad*16 + r15),
// so fragment reads are lane-contiguous ds_read_b128 (conflict-free).
template <int EPI>
__global__ __launch_bounds__(256) void gemm_nt(const u16* __restrict__ A,
                                               const u16* __restrict__ W,
                                               float* __restrict__ Cf,
                                               u16* __restrict__ Cb,
                                               const float* __restrict__ bias,
                                               const float* __restrict__ resid,
                                               int M, int N, int K) {
  __shared__ bf16x8v As4[1024];
  __shared__ bf16x8v Ws4[1024];
  int tid = threadIdx.x;
  int wave = tid >> 6, lane = tid & 63;
  int wm = wave >> 1, wn = wave & 1;
  int lr = lane & 15, quad = lane >> 4;
  int m0 = blockIdx.y * 128, n0 = blockIdx.x * 128;

  f32x4v acc[4][4];
#pragma unroll
  for (int i = 0; i < 4; i++)
#pragma unroll
    for (int j = 0; j < 4; j++) {
      f32x4v z = {0.f, 0.f, 0.f, 0.f};
      acc[i][j] = z;
    }

  for (int k0 = 0; k0 < K; k0 += 64) {
#pragma unroll
    for (int pidx = 0; pidx < 4; ++pidx) {
      int c = pidx * 256 + tid;          // 1024 16B chunks per tile
      int row = c >> 3, col8 = c & 7;    // row 0..127, col8 0..7 (8 bf16 each)
      int lidx = (((row >> 4) * 2 + (col8 >> 2)) << 6) + ((col8 & 3) << 4) + (row & 15);
      As4[lidx] = *(const bf16x8v*)(A + (size_t)(m0 + row) * K + (k0 + col8 * 8));
      Ws4[lidx] = *(const bf16x8v*)(W + (size_t)(n0 + row) * K + (k0 + col8 * 8));
    }
    __syncthreads();
#pragma unroll
    for (int kk = 0; kk < 2; ++kk) {
      bf16x8v af[4], bw[4];
#pragma unroll
      for (int i = 0; i < 4; i++) af[i] = As4[(((wm * 4 + i) * 2 + kk) << 6) + lane];
#pragma unroll
      for (int j = 0; j < 4; j++) bw[j] = Ws4[(((wn * 4 + j) * 2 + kk) << 6) + lane];
#pragma unroll
      for (int i = 0; i < 4; i++)
#pragma unroll
        for (int j = 0; j < 4; j++)
          acc[i][j] = __builtin_amdgcn_mfma_f32_16x16x32_bf16(af[i], bw[j], acc[i][j], 0, 0, 0);
    }
    __syncthreads();
  }

  // Epilogue. D mapping (verified): row = quad*4 + r, col = lane&15.
#pragma unroll
  for (int i = 0; i < 4; i++) {
#pragma unroll
    for (int j = 0; j < 4; j++) {
#pragma unroll
      for (int r = 0; r < 4; r++) {
        int gr = m0 + wm * 64 + i * 16 + quad * 4 + r;
        int gc = n0 + wn * 64 + j * 16 + lr;
        size_t idx = (size_t)gr * N + gc;
        float v = acc[i][j][r];
        if constexpr (EPI == EPI_F32_BIAS_RES) {
          Cf[idx] = v + bias[gc] + resid[idx];
        } else if constexpr (EPI == EPI_BF16_PLAIN) {
          Cb[idx] = f2bf(v);
        } else {  // EPI_BF16_GELU
          v += bias[gc];
          float z = 0.7978845608028654f * (v + 0.044715f * v * v * v);
          float t = 2.f / (1.f + __expf(-2.f * z)) - 1.f;  // tanh(z)
          Cb[idx] = f2bf(0.5f * v * (1.f + t));
        }
      }
    }
  }
}

// Causal attention, online softmax. One wave per query row; 64-key tiles.
// qkv: bf16 [TOK, 3072] (Q|K|V). ctx out: bf16 [TOK, 1024].
__global__ __launch_bounds__(256) void attn_kernel(const u16* __restrict__ qkv,
                                                   u16* __restrict__ ctx) {
  __shared__ float qsh[4][64];
  int tid = threadIdx.x;
  int wave = tid >> 6, lane = tid & 63;
  int bid = blockIdx.x;
  int qgrp = bid & (SEQL / 4 - 1);  // 512 groups of 4 rows
  int bh = bid >> 9;
  int b = bh >> 4, hh = bh & 15;
  int q = qgrp * 4 + wave;
  size_t trow = (size_t)(b * SEQL + q);
  const u16* Qp = qkv + trow * 3072 + hh * 64;
  qsh[wave][lane] = bf2f(Qp[lane]) * 0.125f;  // fold 1/sqrt(64) into q
  __syncthreads();
  const u16* Kbase = qkv + (size_t)(b * SEQL) * 3072 + 1024 + hh * 64;
  const u16* Vbase = qkv + (size_t)(b * SEQL) * 3072 + 2048 + hh * 64;
  float m = -INFINITY, l = 0.f, o = 0.f;
  for (int ks = 0; ks <= q; ks += 64) {
    int kt = ks + lane;
    float s = -INFINITY;
    if (kt <= q) {
      const ushort8v* kp = (const ushort8v*)(Kbase + (size_t)kt * 3072);
      const float4* qv4 = (const float4*)(&qsh[wave][0]);
      float sa = 0.f, sb = 0.f;
#pragma unroll
      for (int c = 0; c < 8; ++c) {
        ushort8v kv = kp[c];
        float4 qa = qv4[2 * c], qb = qv4[2 * c + 1];
        sa += bf2f(kv[0]) * qa.x + bf2f(kv[2]) * qa.z + bf2f(kv[4]) * qb.x + bf2f(kv[6]) * qb.z;
        sb += bf2f(kv[1]) * qa.y + bf2f(kv[3]) * qa.w + bf2f(kv[5]) * qb.y + bf2f(kv[7]) * qb.w;
      }
      s = sa + sb;
    }
    float tm = s;
#pragma unroll
    for (int off = 32; off; off >>= 1) tm = fmaxf(tm, __shfl_xor(tm, off, 64));
    float mn = fmaxf(m, tm);
    float alpha = __expf(m - mn);   // first tile: exp(-inf)=0
    float pp = __expf(s - mn);      // masked lanes: exp(-inf)=0
    float ps = pp;
#pragma unroll
    for (int off = 32; off; off >>= 1) ps += __shfl_xor(ps, off, 64);
    l = l * alpha + ps;
    o *= alpha;
    const u16* vp = Vbase + (size_t)ks * 3072 + lane;  // lane = head dim
    float o0 = 0, o1 = 0, o2 = 0, o3 = 0;
#pragma unroll
    for (int j4 = 0; j4 < 16; ++j4) {
      o0 += __shfl(pp, 4 * j4 + 0, 64) * bf2f(vp[(size_t)(4 * j4 + 0) * 3072]);
      o1 += __shfl(pp, 4 * j4 + 1, 64) * bf2f(vp[(size_t)(4 * j4 + 1) * 3072]);
      o2 += __shfl(pp, 4 * j4 + 2, 64) * bf2f(vp[(size_t)(4 * j4 + 2) * 3072]);
      o3 += __shfl(pp, 4 * j4 + 3, 64) * bf2f(vp[(size_t)(4 * j4 + 3) * 3072]);
    }
    o += (o0 + o1) + (o2 + o3);
    m = mn;
  }
  ctx[trow * D_EMBD + hh * 64 + lane] = f2bf(o / l);
}

extern "C" void kernel_launch(void* const* d_in, const int* in_sizes, int n_in,
                              void* d_out, int out_size, void* d_ws, size_t ws_size,
                              hipStream_t stream) {
  const float* x    = (const float*)d_in[0];
  const float* wq   = (const float*)d_in[1];
  const float* wk   = (const float*)d_in[2];
  const float* wv   = (const float*)d_in[3];
  const float* wo   = (const float*)d_in[4];
  const float* bo   = (const float*)d_in[5];
  const float* w1   = (const float*)d_in[6];
  const float* b1   = (const float*)d_in[7];
  const float* w2   = (const float*)d_in[8];
  const float* b2   = (const float*)d_in[9];
  const float* ln1s = (const float*)d_in[10];
  const float* ln1b = (const float*)d_in[11];
  const float* ln2s = (const float*)d_in[12];
  const float* ln2b = (const float*)d_in[13];
  float* out = (float*)d_out;

  char* base = (char*)d_ws;
  size_t off = 0;
  auto alloc = [&](size_t bytes) {
    char* r = base + off;
    off += (bytes + 255) & ~(size_t)255;
    return r;
  };
  u16*   wcat = (u16*)alloc((size_t)3072 * 1024 * 2);  // [wq;wk;wv] bf16
  u16*   wob  = (u16*)alloc((size_t)1024 * 1024 * 2);
  u16*   w1b  = (u16*)alloc((size_t)4096 * 1024 * 2);
  u16*   w2b  = (u16*)alloc((size_t)1024 * 4096 * 2);
  u16*   xn   = (u16*)alloc((size_t)TOK * 1024 * 2);   // ln1(x) bf16
  u16*   qkv  = (u16*)alloc((size_t)TOK * 3072 * 2);   // Q|K|V bf16
  u16*   ctx  = (u16*)alloc((size_t)TOK * 1024 * 2);   // attention out bf16
  float* hbuf = (float*)alloc((size_t)TOK * 1024 * 4); // residual h f32
  u16*   ybuf = (u16*)alloc((size_t)TOK * 1024 * 2);   // ln2(h) bf16
  u16*   gbuf = (u16*)alloc((size_t)TOK * 4096 * 2);   // gelu(ff1) bf16

  // weight conversions (must run every call: ws is re-poisoned)
  cvt_kernel<<<4096, 256, 0, stream>>>(wq, wcat, 1024 * 1024);
  cvt_kernel<<<4096, 256, 0, stream>>>(wk, wcat + 1024 * 1024, 1024 * 1024);
  cvt_kernel<<<4096, 256, 0, stream>>>(wv, wcat + 2 * 1024 * 1024, 1024 * 1024);
  cvt_kernel<<<4096, 256, 0, stream>>>(wo, wob, 1024 * 1024);
  cvt_kernel<<<16384, 256, 0, stream>>>(w1, w1b, 4096 * 1024);
  cvt_kernel<<<16384, 256, 0, stream>>>(w2, w2b, 4096 * 1024);

  // ln1 -> QKV gemm -> attention
  ln_kernel<<<TOK, 256, 0, stream>>>(x, ln1s, ln1b, xn);
  gemm_nt<EPI_BF16_PLAIN><<<dim3(24, 32), 256, 0, stream>>>(
      xn, wcat, nullptr, qkv, nullptr, nullptr, TOK, 3072, 1024);
  attn_kernel<<<BATCHN * NHEADS * (SEQL / 4), 256, 0, stream>>>(qkv, ctx);
  // h = x + ctx @ wo^T + bo
  gemm_nt<EPI_F32_BIAS_RES><<<dim3(8, 32), 256, 0, stream>>>(
      ctx, wob, hbuf, nullptr, bo, x, TOK, 1024, 1024);
  // MLP
  ln_kernel<<<TOK, 256, 0, stream>>>(hbuf, ln2s, ln2b, ybuf);
  gemm_nt<EPI_BF16_GELU><<<dim3(32, 32), 256, 0, stream>>>(
      ybuf, w1b, nullptr, gbuf, b1, nullptr, TOK, 4096, 1024);
  // out = h + g @ w2^T + b2
  gemm_nt<EPI_F32_BIAS_RES><<<dim3(8, 32), 256, 0, stream>>>(
      gbuf, w2b, out, nullptr, b2, hbuf, TOK, 1024, 4096);
}

// Round 2
// 600.323 us; speedup vs baseline: 3.5028x; 3.5028x over previous
//
#include <hip/hip_runtime.h>
#include <math.h>

typedef unsigned short u16;
typedef __attribute__((ext_vector_type(8))) __bf16 bf16x8v;
typedef __attribute__((ext_vector_type(8))) unsigned short ushort8v;
typedef __attribute__((ext_vector_type(4))) float f32x4v;

#define D_EMBD 1024
#define NHEADS 16
#define DHEAD  64
#define DFF    4096
#define BATCHN 2
#define SEQL   2048
#define TOK    (BATCHN*SEQL)

#define EPI_F32_BIAS_RES 1
#define EPI_BF16_GELU    2
#define EPI_BF16_PLAIN   3

__device__ __forceinline__ float bf2f(u16 s) {
  return __builtin_bit_cast(float, (unsigned)s << 16);
}
__device__ __forceinline__ u16 f2bf(float f) {
  unsigned u = __builtin_bit_cast(unsigned, f);
  unsigned r = u + 0x7fffu + ((u >> 16) & 1u);
  return (u16)(r >> 16);
}

// f32 -> bf16 elementwise (weights)
__global__ __launch_bounds__(256) void cvt_kernel(const float* __restrict__ src,
                                                  u16* __restrict__ dst, int n) {
  int i = blockIdx.x * 256 + threadIdx.x;
  if (i < n) dst[i] = f2bf(src[i]);
}

// LayerNorm over D=1024, one block per row, writes bf16
__global__ __launch_bounds__(256) void ln_kernel(const float* __restrict__ x,
                                                 const float* __restrict__ sc,
                                                 const float* __restrict__ sh,
                                                 u16* __restrict__ out) {
  int row = blockIdx.x, tid = threadIdx.x;
  const float4* xr = (const float4*)(x + (size_t)row * D_EMBD);
  float4 v = xr[tid];
  float s  = (v.x + v.y) + (v.z + v.w);
  float s2 = (v.x * v.x + v.y * v.y) + (v.z * v.z + v.w * v.w);
#pragma unroll
  for (int off = 32; off; off >>= 1) {
    s  += __shfl_xor(s, off, 64);
    s2 += __shfl_xor(s2, off, 64);
  }
  __shared__ float rs[4], rs2[4];
  int wave = tid >> 6, lane = tid & 63;
  if (lane == 0) { rs[wave] = s; rs2[wave] = s2; }
  __syncthreads();
  s  = (rs[0] + rs[1]) + (rs[2] + rs[3]);
  s2 = (rs2[0] + rs2[1]) + (rs2[2] + rs2[3]);
  float mean = s * (1.f / 1024.f);
  float var  = s2 * (1.f / 1024.f) - mean * mean;
  float rstd = rsqrtf(var + 1e-6f);
  float4 scv = ((const float4*)sc)[tid];
  float4 shv = ((const float4*)sh)[tid];
  u16* op = out + (size_t)row * D_EMBD + tid * 4;
  op[0] = f2bf((v.x - mean) * rstd * scv.x + shv.x);
  op[1] = f2bf((v.y - mean) * rstd * scv.y + shv.y);
  op[2] = f2bf((v.z - mean) * rstd * scv.z + shv.z);
  op[3] = f2bf((v.w - mean) * rstd * scv.w + shv.w);
}

// C[M,N] = A[M,K] @ W[N,K]^T, bf16 inputs, f32 accumulate, fused epilogues.
template <int EPI>
__global__ __launch_bounds__(256) void gemm_nt(const u16* __restrict__ A,
                                               const u16* __restrict__ W,
                                               float* __restrict__ Cf,
                                               u16* __restrict__ Cb,
                                               const float* __restrict__ bias,
                                               const float* __restrict__ resid,
                                               int M, int N, int K) {
  __shared__ bf16x8v As4[1024];
  __shared__ bf16x8v Ws4[1024];
  int tid = threadIdx.x;
  int wave = tid >> 6, lane = tid & 63;
  int wm = wave >> 1, wn = wave & 1;
  int lr = lane & 15, quad = lane >> 4;
  int m0 = blockIdx.y * 128, n0 = blockIdx.x * 128;

  f32x4v acc[4][4];
#pragma unroll
  for (int i = 0; i < 4; i++)
#pragma unroll
    for (int j = 0; j < 4; j++) {
      f32x4v z = {0.f, 0.f, 0.f, 0.f};
      acc[i][j] = z;
    }

  for (int k0 = 0; k0 < K; k0 += 64) {
#pragma unroll
    for (int pidx = 0; pidx < 4; ++pidx) {
      int c = pidx * 256 + tid;
      int row = c >> 3, col8 = c & 7;
      int lidx = (((row >> 4) * 2 + (col8 >> 2)) << 6) + ((col8 & 3) << 4) + (row & 15);
      As4[lidx] = *(const bf16x8v*)(A + (size_t)(m0 + row) * K + (k0 + col8 * 8));
      Ws4[lidx] = *(const bf16x8v*)(W + (size_t)(n0 + row) * K + (k0 + col8 * 8));
    }
    __syncthreads();
#pragma unroll
    for (int kk = 0; kk < 2; ++kk) {
      bf16x8v af[4], bw[4];
#pragma unroll
      for (int i = 0; i < 4; i++) af[i] = As4[(((wm * 4 + i) * 2 + kk) << 6) + lane];
#pragma unroll
      for (int j = 0; j < 4; j++) bw[j] = Ws4[(((wn * 4 + j) * 2 + kk) << 6) + lane];
#pragma unroll
      for (int i = 0; i < 4; i++)
#pragma unroll
        for (int j = 0; j < 4; j++)
          acc[i][j] = __builtin_amdgcn_mfma_f32_16x16x32_bf16(af[i], bw[j], acc[i][j], 0, 0, 0);
    }
    __syncthreads();
  }

#pragma unroll
  for (int i = 0; i < 4; i++) {
#pragma unroll
    for (int j = 0; j < 4; j++) {
#pragma unroll
      for (int r = 0; r < 4; r++) {
        int gr = m0 + wm * 64 + i * 16 + quad * 4 + r;
        int gc = n0 + wn * 64 + j * 16 + lr;
        size_t idx = (size_t)gr * N + gc;
        float v = acc[i][j][r];
        if constexpr (EPI == EPI_F32_BIAS_RES) {
          Cf[idx] = v + bias[gc] + resid[idx];
        } else if constexpr (EPI == EPI_BF16_PLAIN) {
          Cb[idx] = f2bf(v);
        } else {
          v += bias[gc];
          float z = 0.7978845608028654f * (v + 0.044715f * v * v * v);
          float t = 2.f / (1.f + __expf(-2.f * z)) - 1.f;
          Cb[idx] = f2bf(0.5f * v * (1.f + t));
        }
      }
    }
  }
}

// MFMA flash attention (causal). Block = one (b,h) x 64-query tile; 4 waves,
// each wave owns 16 q-rows. K-tile staged in MFMA B-fragment order; V-tile
// staged transposed (Vt[dim][key]) with XOR bank swizzle on the key-block;
// P goes C-layout -> LDS -> A-layout (per-wave private region, no barrier).
// qkv: bf16 [TOK, 3072] (Q|K|V). ctx: bf16 [TOK, 1024].
#define VTS 72   // Vt / Ps row stride in elements
__global__ __launch_bounds__(256) void attn_kernel(const u16* __restrict__ qkv,
                                                   u16* __restrict__ ctx) {
  __shared__ bf16x8v Kf[512];        // 8 KB, fragment order
  __shared__ u16 Vt[64 * VTS];       // 9 KB, V^T swizzled
  __shared__ u16 Ps[4 * 16 * VTS];   // 9 KB, per-wave P
  int tid = threadIdx.x;
  int wave = tid >> 6, lane = tid & 63;
  int lr = lane & 15, quad = lane >> 4;
  int t = blockIdx.x;                 // q-tile index, 0..31
  int bh = blockIdx.y;
  int b = bh >> 4, h = bh & 15;
  int q0 = t * 64;
  const u16* qkvb = qkv + (size_t)(b * SEQL) * 3072;
  // Q fragments: A[m=lane&15 (q-row), k=quad*8+j (+32*kk)]
  int qrow = q0 + wave * 16 + lr;
  const u16* Qp = qkvb + (size_t)qrow * 3072 + h * 64 + quad * 8;
  bf16x8v qf0 = *(const bf16x8v*)(Qp);
  bf16x8v qf1 = *(const bf16x8v*)(Qp + 32);
  const u16* Kbase = qkvb + 1024 + h * 64;
  const u16* Vbase = qkvb + 2048 + h * 64;

  float mrow[4], lrow[4];
  f32x4v accO[4];
#pragma unroll
  for (int r = 0; r < 4; r++) {
    mrow[r] = -INFINITY;
    lrow[r] = 0.f;
    f32x4v z = {0.f, 0.f, 0.f, 0.f};
    accO[r] = z;
  }

  int nkt = t + 1;
  for (int kt = 0; kt < nkt; ++kt) {
    int ks = kt * 64;
    __syncthreads();
    // ---- stage K (fragment order) and V (transposed + swizzled) ----
#pragma unroll
    for (int p = 0; p < 2; ++p) {
      int c = p * 256 + tid;
      int key = c >> 3, c8 = c & 7;
      bf16x8v kv = *(const bf16x8v*)(Kbase + (size_t)(ks + key) * 3072 + c8 * 8);
      int lidx = (((key >> 4) * 2 + (c8 >> 2)) << 6) + ((c8 & 3) << 4) + (key & 15);
      Kf[lidx] = kv;
      ushort8v vv = *(const ushort8v*)(Vbase + (size_t)(ks + key) * 3072 + c8 * 8);
      int dim0 = c8 * 8;
      int vcol = (((key >> 3) ^ (c8 & 7)) << 3) + (key & 7);
#pragma unroll
      for (int j = 0; j < 8; ++j) Vt[(dim0 + j) * VTS + vcol] = vv[j];
    }
    __syncthreads();
    // ---- S = Q K^T ----
    f32x4v accS[4];
#pragma unroll
    for (int jb = 0; jb < 4; jb++) {
      f32x4v z = {0.f, 0.f, 0.f, 0.f};
      accS[jb] = z;
    }
#pragma unroll
    for (int jb = 0; jb < 4; jb++) {
      accS[jb] = __builtin_amdgcn_mfma_f32_16x16x32_bf16(qf0, Kf[((jb * 2 + 0) << 6) + lane], accS[jb], 0, 0, 0);
      accS[jb] = __builtin_amdgcn_mfma_f32_16x16x32_bf16(qf1, Kf[((jb * 2 + 1) << 6) + lane], accS[jb], 0, 0, 0);
    }
    // ---- causal mask (diagonal tile only; ks/q0 wave-uniform) ----
    if (ks == q0) {
#pragma unroll
      for (int jb = 0; jb < 4; jb++)
#pragma unroll
        for (int r = 0; r < 4; r++) {
          int keyg = jb * 16 + lr;
          int rowg = wave * 16 + quad * 4 + r;
          if (keyg > rowg) accS[jb][r] = -INFINITY;
        }
    }
    // ---- online softmax (scale 1/8 folded into exp) ----
    float mx[4], al[4], psum[4];
#pragma unroll
    for (int r = 0; r < 4; r++)
      mx[r] = fmaxf(fmaxf(accS[0][r], accS[1][r]), fmaxf(accS[2][r], accS[3][r]));
#pragma unroll
    for (int off = 8; off; off >>= 1)
#pragma unroll
      for (int r = 0; r < 4; r++) mx[r] = fmaxf(mx[r], __shfl_xor(mx[r], off, 64));
#pragma unroll
    for (int r = 0; r < 4; r++) {
      float mn = fmaxf(mrow[r], mx[r]);
      al[r] = __expf((mrow[r] - mn) * 0.125f);
      mrow[r] = mn;
    }
#pragma unroll
    for (int jb = 0; jb < 4; jb++)
#pragma unroll
      for (int r = 0; r < 4; r++)
        accS[jb][r] = __expf((accS[jb][r] - mrow[r]) * 0.125f);
#pragma unroll
    for (int r = 0; r < 4; r++)
      psum[r] = (accS[0][r] + accS[1][r]) + (accS[2][r] + accS[3][r]);
#pragma unroll
    for (int off = 8; off; off >>= 1)
#pragma unroll
      for (int r = 0; r < 4; r++) psum[r] += __shfl_xor(psum[r], off, 64);
#pragma unroll
    for (int r = 0; r < 4; r++) lrow[r] = lrow[r] * al[r] + psum[r];
#pragma unroll
    for (int nb = 0; nb < 4; nb++)
#pragma unroll
      for (int r = 0; r < 4; r++) accO[nb][r] *= al[r];
    // ---- P: C-layout -> LDS (per-wave region) ----
    u16* myP = Ps + wave * 16 * VTS;
#pragma unroll
    for (int jb = 0; jb < 4; jb++)
#pragma unroll
      for (int r = 0; r < 4; r++)
        myP[(quad * 4 + r) * VTS + jb * 16 + lr] = f2bf(accS[jb][r]);
    // ---- O += P V ----
#pragma unroll
    for (int kk = 0; kk < 2; ++kk) {
      bf16x8v pa = *(const bf16x8v*)(myP + lr * VTS + quad * 8 + kk * 32);
#pragma unroll
      for (int nb = 0; nb < 4; nb++) {
        int dim = nb * 16 + lr;
        int f = (dim >> 3) & 7;
        bf16x8v vfr = *(const bf16x8v*)(Vt + dim * VTS + (((quad + 4 * kk) ^ f) << 3));
        accO[nb] = __builtin_amdgcn_mfma_f32_16x16x32_bf16(pa, vfr, accO[nb], 0, 0, 0);
      }
    }
  }
  // ---- epilogue: O / l ----
  float rinv[4];
#pragma unroll
  for (int r = 0; r < 4; r++) rinv[r] = 1.f / lrow[r];
#pragma unroll
  for (int nb = 0; nb < 4; nb++)
#pragma unroll
    for (int r = 0; r < 4; r++) {
      int rowg = q0 + wave * 16 + quad * 4 + r;
      ctx[(size_t)(b * SEQL + rowg) * D_EMBD + h * 64 + nb * 16 + lr] =
          f2bf(accO[nb][r] * rinv[r]);
    }
}

extern "C" void kernel_launch(void* const* d_in, const int* in_sizes, int n_in,
                              void* d_out, int out_size, void* d_ws, size_t ws_size,
                              hipStream_t stream) {
  const float* x    = (const float*)d_in[0];
  const float* wq   = (const float*)d_in[1];
  const float* wk   = (const float*)d_in[2];
  const float* wv   = (const float*)d_in[3];
  const float* wo   = (const float*)d_in[4];
  const float* bo   = (const float*)d_in[5];
  const float* w1   = (const float*)d_in[6];
  const float* b1   = (const float*)d_in[7];
  const float* w2   = (const float*)d_in[8];
  const float* b2   = (const float*)d_in[9];
  const float* ln1s = (const float*)d_in[10];
  const float* ln1b = (const float*)d_in[11];
  const float* ln2s = (const float*)d_in[12];
  const float* ln2b = (const float*)d_in[13];
  float* out = (float*)d_out;

  char* base = (char*)d_ws;
  size_t off = 0;
  auto alloc = [&](size_t bytes) {
    char* r = base + off;
    off += (bytes + 255) & ~(size_t)255;
    return r;
  };
  u16*   wcat = (u16*)alloc((size_t)3072 * 1024 * 2);
  u16*   wob  = (u16*)alloc((size_t)1024 * 1024 * 2);
  u16*   w1b  = (u16*)alloc((size_t)4096 * 1024 * 2);
  u16*   w2b  = (u16*)alloc((size_t)1024 * 4096 * 2);
  u16*   xn   = (u16*)alloc((size_t)TOK * 1024 * 2);
  u16*   qkv  = (u16*)alloc((size_t)TOK * 3072 * 2);
  u16*   ctx  = (u16*)alloc((size_t)TOK * 1024 * 2);
  float* hbuf = (float*)alloc((size_t)TOK * 1024 * 4);
  u16*   ybuf = (u16*)alloc((size_t)TOK * 1024 * 2);
  u16*   gbuf = (u16*)alloc((size_t)TOK * 4096 * 2);

  cvt_kernel<<<4096, 256, 0, stream>>>(wq, wcat, 1024 * 1024);
  cvt_kernel<<<4096, 256, 0, stream>>>(wk, wcat + 1024 * 1024, 1024 * 1024);
  cvt_kernel<<<4096, 256, 0, stream>>>(wv, wcat + 2 * 1024 * 1024, 1024 * 1024);
  cvt_kernel<<<4096, 256, 0, stream>>>(wo, wob, 1024 * 1024);
  cvt_kernel<<<16384, 256, 0, stream>>>(w1, w1b, 4096 * 1024);
  cvt_kernel<<<16384, 256, 0, stream>>>(w2, w2b, 4096 * 1024);

  ln_kernel<<<TOK, 256, 0, stream>>>(x, ln1s, ln1b, xn);
  gemm_nt<EPI_BF16_PLAIN><<<dim3(24, 32), 256, 0, stream>>>(
      xn, wcat, nullptr, qkv, nullptr, nullptr, TOK, 3072, 1024);
  attn_kernel<<<dim3(32, 32), 256, 0, stream>>>(qkv, ctx);
  gemm_nt<EPI_F32_BIAS_RES><<<dim3(8, 32), 256, 0, stream>>>(
      ctx, wob, hbuf, nullptr, bo, x, TOK, 1024, 1024);
  ln_kernel<<<TOK, 256, 0, stream>>>(hbuf, ln2s, ln2b, ybuf);
  gemm_nt<EPI_BF16_GELU><<<dim3(32, 32), 256, 0, stream>>>(
      ybuf, w1b, nullptr, gbuf, b1, nullptr, TOK, 4096, 1024);
  gemm_nt<EPI_F32_BIAS_RES><<<dim3(8, 32), 256, 0, stream>>>(
      gbuf, w2b, out, nullptr, b2, hbuf, TOK, 1024, 4096);
}

// Round 3
// 484.925 us; speedup vs baseline: 4.3363x; 1.2380x over previous
//
#include <hip/hip_runtime.h>
#include <math.h>

typedef unsigned short u16;
typedef __attribute__((ext_vector_type(8))) __bf16 bf16x8v;
typedef __attribute__((ext_vector_type(8))) unsigned short ushort8v;
typedef __attribute__((ext_vector_type(4))) float f32x4v;

#define D_EMBD 1024
#define NHEADS 16
#define DHEAD  64
#define DFF    4096
#define BATCHN 2
#define SEQL   2048
#define TOK    (BATCHN*SEQL)

#define EPI_F32_BIAS_RES 1
#define EPI_BF16_GELU    2
#define EPI_BF16_PLAIN   3

__device__ __forceinline__ float bf2f(u16 s) {
  return __builtin_bit_cast(float, (unsigned)s << 16);
}
__device__ __forceinline__ u16 f2bf(float f) {
  unsigned u = __builtin_bit_cast(unsigned, f);
  unsigned r = u + 0x7fffu + ((u >> 16) & 1u);
  return (u16)(r >> 16);
}

// async global->LDS, 16B per lane; LDS dest = wave-uniform base + lane*16
#define GLOAD16(gp, lp)                                                        \
  __builtin_amdgcn_global_load_lds(                                            \
      (__attribute__((address_space(1))) void*)(void*)(gp),                    \
      (__attribute__((address_space(3))) void*)(void*)(lp), 16, 0, 0)

// f32x4 -> bf16x4 elementwise (weights)
__global__ __launch_bounds__(256) void cvt_kernel(const float* __restrict__ src,
                                                  u16* __restrict__ dst, int n4) {
  int i = blockIdx.x * 256 + threadIdx.x;
  if (i < n4) {
    float4 v = ((const float4*)src)[i];
    ushort4 o;
    o.x = f2bf(v.x); o.y = f2bf(v.y); o.z = f2bf(v.z); o.w = f2bf(v.w);
    ((ushort4*)dst)[i] = o;
  }
}

// LayerNorm over D=1024, one block per row, writes bf16
__global__ __launch_bounds__(256) void ln_kernel(const float* __restrict__ x,
                                                 const float* __restrict__ sc,
                                                 const float* __restrict__ sh,
                                                 u16* __restrict__ out) {
  int row = blockIdx.x, tid = threadIdx.x;
  const float4* xr = (const float4*)(x + (size_t)row * D_EMBD);
  float4 v = xr[tid];
  float s  = (v.x + v.y) + (v.z + v.w);
  float s2 = (v.x * v.x + v.y * v.y) + (v.z * v.z + v.w * v.w);
#pragma unroll
  for (int off = 32; off; off >>= 1) {
    s  += __shfl_xor(s, off, 64);
    s2 += __shfl_xor(s2, off, 64);
  }
  __shared__ float rs[4], rs2[4];
  int wave = tid >> 6, lane = tid & 63;
  if (lane == 0) { rs[wave] = s; rs2[wave] = s2; }
  __syncthreads();
  s  = (rs[0] + rs[1]) + (rs[2] + rs[3]);
  s2 = (rs2[0] + rs2[1]) + (rs2[2] + rs2[3]);
  float mean = s * (1.f / 1024.f);
  float var  = s2 * (1.f / 1024.f) - mean * mean;
  float rstd = rsqrtf(var + 1e-6f);
  float4 scv = ((const float4*)sc)[tid];
  float4 shv = ((const float4*)sh)[tid];
  u16* op = out + (size_t)row * D_EMBD + tid * 4;
  op[0] = f2bf((v.x - mean) * rstd * scv.x + shv.x);
  op[1] = f2bf((v.y - mean) * rstd * scv.y + shv.y);
  op[2] = f2bf((v.z - mean) * rstd * scv.z + shv.z);
  op[3] = f2bf((v.w - mean) * rstd * scv.w + shv.w);
}

// C[M,N] = A[M,K] @ W[N,K]^T, bf16, f32 acc, fused epilogues.
// 128x128 tile, BK=64, m97-style: global_load_lds width-16 straight into
// fragment-order LDS (chunk lidx = (rowblk*2+kkblk)*64 + (col8&3)*16 + row&15).
template <int EPI>
__global__ __launch_bounds__(256) void gemm_nt(const u16* __restrict__ A,
                                               const u16* __restrict__ W,
                                               float* __restrict__ Cf,
                                               u16* __restrict__ Cb,
                                               const float* __restrict__ bias,
                                               const float* __restrict__ resid,
                                               int M, int N, int K) {
  __shared__ u16 As[8192];  // 16 KB
  __shared__ u16 Ws[8192];
  int tid = threadIdx.x;
  int wave = tid >> 6, lane = tid & 63;
  int wm = wave >> 1, wn = wave & 1;
  int lr = lane & 15, quad = lane >> 4;
  int m0 = blockIdx.y * 128, n0 = blockIdx.x * 128;

  f32x4v acc[4][4];
#pragma unroll
  for (int i = 0; i < 4; i++)
#pragma unroll
    for (int j = 0; j < 4; j++) {
      f32x4v z = {0.f, 0.f, 0.f, 0.f};
      acc[i][j] = z;
    }

  for (int k0 = 0; k0 < K; k0 += 64) {
#pragma unroll
    for (int p = 0; p < 4; ++p) {
      int q = wave * 4 + p;                 // 0..15: rowblk=q>>1, kkblk=q&1
      int row = ((q >> 1) << 4) + lr;
      int col = k0 + (((q & 1) << 2) + quad) * 8;
      GLOAD16(A + (size_t)(m0 + row) * K + col, (char*)As + q * 1024);
      GLOAD16(W + (size_t)(n0 + row) * K + col, (char*)Ws + q * 1024);
    }
    __syncthreads();   // drains vmcnt -> LDS tiles ready
    const bf16x8v* As4 = (const bf16x8v*)As;
    const bf16x8v* Ws4 = (const bf16x8v*)Ws;
#pragma unroll
    for (int kk = 0; kk < 2; ++kk) {
      bf16x8v af[4], bw[4];
#pragma unroll
      for (int i = 0; i < 4; i++) af[i] = As4[(((wm * 4 + i) * 2 + kk) << 6) + lane];
#pragma unroll
      for (int j = 0; j < 4; j++) bw[j] = Ws4[(((wn * 4 + j) * 2 + kk) << 6) + lane];
#pragma unroll
      for (int i = 0; i < 4; i++)
#pragma unroll
        for (int j = 0; j < 4; j++)
          acc[i][j] = __builtin_amdgcn_mfma_f32_16x16x32_bf16(af[i], bw[j], acc[i][j], 0, 0, 0);
    }
    __syncthreads();   // protect LDS before next iter's staging
  }

#pragma unroll
  for (int i = 0; i < 4; i++) {
#pragma unroll
    for (int j = 0; j < 4; j++) {
#pragma unroll
      for (int r = 0; r < 4; r++) {
        int gr = m0 + wm * 64 + i * 16 + quad * 4 + r;
        int gc = n0 + wn * 64 + j * 16 + lr;
        size_t idx = (size_t)gr * N + gc;
        float v = acc[i][j][r];
        if constexpr (EPI == EPI_F32_BIAS_RES) {
          Cf[idx] = v + bias[gc] + resid[idx];
        } else if constexpr (EPI == EPI_BF16_PLAIN) {
          Cb[idx] = f2bf(v);
        } else {
          v += bias[gc];
          float z = 0.7978845608028654f * (v + 0.044715f * v * v * v);
          float t = 2.f / (1.f + __expf(-2.f * z)) - 1.f;
          Cb[idx] = f2bf(0.5f * v * (1.f + t));
        }
      }
    }
  }
}

// ---------------- MFMA flash attention (causal) ----------------
// 1D grid of 1024 blocks; balanced t-permutation so each CU's 4 blocks sum to
// ~66 k-tiles. Double-buffered K (async global_load_lds, fragment order) and
// V^T (register prefetch + paired-b32 transposed store), ONE barrier per tile.
#define VTS 72
__device__ __forceinline__ void stage_k(const u16* Kbase, int ks, u16* kfbuf,
                                        int wave, int lr, int quad) {
#pragma unroll
  for (int p = 0; p < 2; ++p) {
    int q = wave * 2 + p;                  // 0..7: keyblk=q>>1, kkblk=q&1
    int key = ((q >> 1) << 4) + lr;
    int c8 = ((q & 1) << 2) + quad;
    GLOAD16(Kbase + (size_t)(ks + key) * 3072 + c8 * 8, (char*)kfbuf + q * 1024);
  }
}
__device__ __forceinline__ void load_v(const u16* Vbase, int ks, int vkey0, int vc8,
                                       ushort8v& va, ushort8v& vb) {
  va = *(const ushort8v*)(Vbase + (size_t)(ks + vkey0) * 3072 + vc8 * 8);
  vb = *(const ushort8v*)(Vbase + (size_t)(ks + vkey0 + 1) * 3072 + vc8 * 8);
}
__device__ __forceinline__ void write_vt(u16* vt, int vc8, int vcol,
                                         ushort8v va, ushort8v vb) {
#pragma unroll
  for (int j = 0; j < 8; ++j) {
    unsigned pk = (unsigned)va[j] | ((unsigned)vb[j] << 16);
    *(unsigned*)(vt + (size_t)(vc8 * 8 + j) * VTS + vcol) = pk;
  }
}

__global__ __launch_bounds__(256) void attn_kernel(const u16* __restrict__ qkv,
                                                   u16* __restrict__ ctx) {
  __shared__ u16 Kf[2][4096];        // 2 x 8 KB, fragment order
  __shared__ u16 Vt[2][64 * VTS];    // 2 x 9 KB, V^T swizzled
  __shared__ u16 Ps[4 * 16 * VTS];   // 9 KB, per-wave P
  int tid = threadIdx.x;
  int wave = tid >> 6, lane = tid & 63;
  int lr = lane & 15, quad = lane >> 4;
  int id = blockIdx.x;
  int bh = id & 31;
  int k5 = id >> 5, gg = k5 >> 3, jj = k5 & 7;
  int t = (gg == 0) ? jj : (gg == 1) ? 15 - jj : (gg == 2) ? 16 + jj : 31 - jj;
  int b = bh >> 4, h = bh & 15;
  int q0 = t * 64;
  const u16* qkvb = qkv + (size_t)(b * SEQL) * 3072;
  int qrow = q0 + wave * 16 + lr;
  const u16* Qp = qkvb + (size_t)qrow * 3072 + h * 64 + quad * 8;
  bf16x8v qf0 = *(const bf16x8v*)(Qp);
  bf16x8v qf1 = *(const bf16x8v*)(Qp + 32);
  const u16* Kbase = qkvb + 1024 + h * 64;
  const u16* Vbase = qkvb + 2048 + h * 64;
  // V staging assignment: this thread handles keys (vkey0, vkey0+1), dims vc8*8..+7
  int vkey0 = (tid >> 3) * 2, vc8 = tid & 7;
  int vcol = (((vkey0 >> 3) ^ vc8) << 3) + (vkey0 & 7);

  float mrow[4], lrow[4];
  f32x4v accO[4];
#pragma unroll
  for (int r = 0; r < 4; r++) {
    mrow[r] = -INFINITY;
    lrow[r] = 0.f;
    f32x4v z = {0.f, 0.f, 0.f, 0.f};
    accO[r] = z;
  }

  int nkt = t + 1;
  // prologue: stage tile 0 into buffer 0
  {
    stage_k(Kbase, 0, Kf[0], wave, lr, quad);
    ushort8v va, vb;
    load_v(Vbase, 0, vkey0, vc8, va, vb);
    write_vt(Vt[0], vc8, vcol, va, vb);
  }
  __syncthreads();

  for (int kt = 0; kt < nkt; ++kt) {
    int cur = kt & 1, nxt = cur ^ 1;
    ushort8v va, vb;
    bool pre = (kt + 1 < nkt);
    if (pre) {
      stage_k(Kbase, (kt + 1) * 64, Kf[nxt], wave, lr, quad);   // async -> LDS
      load_v(Vbase, (kt + 1) * 64, vkey0, vc8, va, vb);         // -> regs
    }
    const bf16x8v* Kc = (const bf16x8v*)Kf[cur];
    const u16* Vc = Vt[cur];
    // ---- S = Q K^T ----
    f32x4v accS[4];
#pragma unroll
    for (int jb = 0; jb < 4; jb++) {
      f32x4v z = {0.f, 0.f, 0.f, 0.f};
      accS[jb] = z;
    }
#pragma unroll
    for (int jb = 0; jb < 4; jb++) {
      accS[jb] = __builtin_amdgcn_mfma_f32_16x16x32_bf16(qf0, Kc[((jb * 2 + 0) << 6) + lane], accS[jb], 0, 0, 0);
      accS[jb] = __builtin_amdgcn_mfma_f32_16x16x32_bf16(qf1, Kc[((jb * 2 + 1) << 6) + lane], accS[jb], 0, 0, 0);
    }
    if (kt == t) {  // diagonal tile: causal mask
#pragma unroll
      for (int jb = 0; jb < 4; jb++)
#pragma unroll
        for (int r = 0; r < 4; r++) {
          int keyg = jb * 16 + lr;
          int rowg = wave * 16 + quad * 4 + r;
          if (keyg > rowg) accS[jb][r] = -INFINITY;
        }
    }
    // ---- online softmax (scale 1/8 folded into exp) ----
    float mx[4], al[4], psum[4];
#pragma unroll
    for (int r = 0; r < 4; r++)
      mx[r] = fmaxf(fmaxf(accS[0][r], accS[1][r]), fmaxf(accS[2][r], accS[3][r]));
#pragma unroll
    for (int off = 8; off; off >>= 1)
#pragma unroll
      for (int r = 0; r < 4; r++) mx[r] = fmaxf(mx[r], __shfl_xor(mx[r], off, 64));
#pragma unroll
    for (int r = 0; r < 4; r++) {
      float mn = fmaxf(mrow[r], mx[r]);
      al[r] = __expf((mrow[r] - mn) * 0.125f);
      mrow[r] = mn;
    }
#pragma unroll
    for (int jb = 0; jb < 4; jb++)
#pragma unroll
      for (int r = 0; r < 4; r++)
        accS[jb][r] = __expf((accS[jb][r] - mrow[r]) * 0.125f);
#pragma unroll
    for (int r = 0; r < 4; r++)
      psum[r] = (accS[0][r] + accS[1][r]) + (accS[2][r] + accS[3][r]);
#pragma unroll
    for (int off = 8; off; off >>= 1)
#pragma unroll
      for (int r = 0; r < 4; r++) psum[r] += __shfl_xor(psum[r], off, 64);
#pragma unroll
    for (int r = 0; r < 4; r++) lrow[r] = lrow[r] * al[r] + psum[r];
#pragma unroll
    for (int nb = 0; nb < 4; nb++)
#pragma unroll
      for (int r = 0; r < 4; r++) accO[nb][r] *= al[r];
    // ---- P: C-layout -> per-wave LDS ----
    u16* myP = Ps + wave * 16 * VTS;
#pragma unroll
    for (int jb = 0; jb < 4; jb++)
#pragma unroll
      for (int r = 0; r < 4; r++)
        myP[(quad * 4 + r) * VTS + jb * 16 + lr] = f2bf(accS[jb][r]);
    // ---- O += P V ----
#pragma unroll
    for (int kk = 0; kk < 2; ++kk) {
      bf16x8v pa = *(const bf16x8v*)(myP + lr * VTS + quad * 8 + kk * 32);
#pragma unroll
      for (int nb = 0; nb < 4; nb++) {
        int dim = nb * 16 + lr;
        int f = (dim >> 3) & 7;
        bf16x8v vfr = *(const bf16x8v*)(Vc + dim * VTS + (((quad + 4 * kk) ^ f) << 3));
        accO[nb] = __builtin_amdgcn_mfma_f32_16x16x32_bf16(pa, vfr, accO[nb], 0, 0, 0);
      }
    }
    if (pre) write_vt(Vt[nxt], vc8, vcol, va, vb);
    __syncthreads();  // single barrier per tile: drains async K + Vt/P writes
  }
  // ---- epilogue: O / l ----
  float rinv[4];
#pragma unroll
  for (int r = 0; r < 4; r++) rinv[r] = 1.f / lrow[r];
#pragma unroll
  for (int nb = 0; nb < 4; nb++)
#pragma unroll
    for (int r = 0; r < 4; r++) {
      int rowg = q0 + wave * 16 + quad * 4 + r;
      ctx[(size_t)(b * SEQL + rowg) * D_EMBD + h * 64 + nb * 16 + lr] =
          f2bf(accO[nb][r] * rinv[r]);
    }
}

extern "C" void kernel_launch(void* const* d_in, const int* in_sizes, int n_in,
                              void* d_out, int out_size, void* d_ws, size_t ws_size,
                              hipStream_t stream) {
  const float* x    = (const float*)d_in[0];
  const float* wq   = (const float*)d_in[1];
  const float* wk   = (const float*)d_in[2];
  const float* wv   = (const float*)d_in[3];
  const float* wo   = (const float*)d_in[4];
  const float* bo   = (const float*)d_in[5];
  const float* w1   = (const float*)d_in[6];
  const float* b1   = (const float*)d_in[7];
  const float* w2   = (const float*)d_in[8];
  const float* b2   = (const float*)d_in[9];
  const float* ln1s = (const float*)d_in[10];
  const float* ln1b = (const float*)d_in[11];
  const float* ln2s = (const float*)d_in[12];
  const float* ln2b = (const float*)d_in[13];
  float* out = (float*)d_out;

  char* base = (char*)d_ws;
  size_t off = 0;
  auto alloc = [&](size_t bytes) {
    char* r = base + off;
    off += (bytes + 255) & ~(size_t)255;
    return r;
  };
  u16*   wcat = (u16*)alloc((size_t)3072 * 1024 * 2);
  u16*   wob  = (u16*)alloc((size_t)1024 * 1024 * 2);
  u16*   w1b  = (u16*)alloc((size_t)4096 * 1024 * 2);
  u16*   w2b  = (u16*)alloc((size_t)1024 * 4096 * 2);
  u16*   xn   = (u16*)alloc((size_t)TOK * 1024 * 2);
  u16*   qkv  = (u16*)alloc((size_t)TOK * 3072 * 2);
  u16*   ctx  = (u16*)alloc((size_t)TOK * 1024 * 2);
  float* hbuf = (float*)alloc((size_t)TOK * 1024 * 4);
  u16*   ybuf = (u16*)alloc((size_t)TOK * 1024 * 2);
  u16*   gbuf = (u16*)alloc((size_t)TOK * 4096 * 2);

  cvt_kernel<<<1024, 256, 0, stream>>>(wq, wcat, 256 * 1024);
  cvt_kernel<<<1024, 256, 0, stream>>>(wk, wcat + 1024 * 1024, 256 * 1024);
  cvt_kernel<<<1024, 256, 0, stream>>>(wv, wcat + 2 * 1024 * 1024, 256 * 1024);
  cvt_kernel<<<1024, 256, 0, stream>>>(wo, wob, 256 * 1024);
  cvt_kernel<<<4096, 256, 0, stream>>>(w1, w1b, 1024 * 1024);
  cvt_kernel<<<4096, 256, 0, stream>>>(w2, w2b, 1024 * 1024);

  ln_kernel<<<TOK, 256, 0, stream>>>(x, ln1s, ln1b, xn);
  gemm_nt<EPI_BF16_PLAIN><<<dim3(24, 32), 256, 0, stream>>>(
      xn, wcat, nullptr, qkv, nullptr, nullptr, TOK, 3072, 1024);
  attn_kernel<<<1024, 256, 0, stream>>>(qkv, ctx);
  gemm_nt<EPI_F32_BIAS_RES><<<dim3(8, 32), 256, 0, stream>>>(
      ctx, wob, hbuf, nullptr, bo, x, TOK, 1024, 1024);
  ln_kernel<<<TOK, 256, 0, stream>>>(hbuf, ln2s, ln2b, ybuf);
  gemm_nt<EPI_BF16_GELU><<<dim3(32, 32), 256, 0, stream>>>(
      ybuf, w1b, nullptr, gbuf, b1, nullptr, TOK, 4096, 1024);
  gemm_nt<EPI_F32_BIAS_RES><<<dim3(8, 32), 256, 0, stream>>>(
      gbuf, w2b, out, nullptr, b2, hbuf, TOK, 1024, 4096);
}